// Round 6
// baseline (90458.472 us; speedup 1.0000x reference)
//
#include <hip/hip_runtime.h>
#include <math.h>

typedef _Float16 h8 __attribute__((ext_vector_type(8)));
typedef float f4 __attribute__((ext_vector_type(4)));
typedef unsigned long long u64;

#define H 1024

// ---- workspace layout (bytes) ----
#define OFF_WRZ0 0ull            // fp16 [2048][1536]
#define OFF_WN0  6291456ull      // fp16 [1024][1536]
#define OFF_WRZ1 9437184ull      // fp16 [2048][2048]
#define OFF_WN1  17825792ull     // fp16 [1024][2048]
#define OFF_H0H  22020096ull     // fp16 [2][64][1024] parity-buffered
#define OFF_H1H  22282240ull     // fp16 [2][64][1024]
#define OFF_RH0  22544384ull     // fp16 [64][1024]
#define OFF_RH1  22675456ull     // fp16 [64][1024]
#define OFF_H0F  22806528ull     // f32 [64][1024]
#define OFF_H1F  23068672ull     // f32 [64][1024]
#define OFF_Z0F  23330816ull     // f32 [64][1024]
#define OFF_Z1F  23592960ull     // f32 [64][1024]
#define OFF_CNT  23855104ull     // u64 [4] stride 16 u64 (128 B/ctr)
#define ZERO_WORDS 458880        // (23855616 - 22020096)/4

// ---------------- LLC-bypass (agent-scope relaxed) helpers — r2/r5-proven ----------------
__device__ __forceinline__ u64 llc_ld64(const void* p) {
  return __hip_atomic_load((const u64*)p, __ATOMIC_RELAXED, __HIP_MEMORY_SCOPE_AGENT);
}
__device__ __forceinline__ unsigned llc_ld32(const void* p) {
  return __hip_atomic_load((const unsigned*)p, __ATOMIC_RELAXED, __HIP_MEMORY_SCOPE_AGENT);
}
__device__ __forceinline__ float llc_ldf(const float* p) {
  return __uint_as_float(llc_ld32(p));
}
__device__ __forceinline__ void llc_st32(void* p, unsigned v) {
  __hip_atomic_store((unsigned*)p, v, __ATOMIC_RELAXED, __HIP_MEMORY_SCOPE_AGENT);
}
union H8U { u64 q[2]; h8 v; };
union H16B { _Float16 h; unsigned short u; };

#define MFMA16(a, b, c) __builtin_amdgcn_mfma_f32_16x16x32_f16((a), (b), (c), 0, 0, 0)

// ---------------- prep: weights fp32->fp16, zero state/counter region ----------------
__global__ __launch_bounds__(256) void prep_kernel(
    const float* __restrict__ wrz0f, const float* __restrict__ wn0f,
    const float* __restrict__ wrz1f, const float* __restrict__ wn1f,
    _Float16* __restrict__ wrz0, _Float16* __restrict__ wn0,
    _Float16* __restrict__ wrz1, _Float16* __restrict__ wn1,
    unsigned* __restrict__ zbase) {
  size_t i = (size_t)blockIdx.x * blockDim.x + threadIdx.x;
  size_t stride = (size_t)gridDim.x * blockDim.x;
  for (size_t k = i; k < 2048ull * 1536ull; k += stride) wrz0[k] = (_Float16)wrz0f[k];
  for (size_t k = i; k < 1024ull * 1536ull; k += stride) wn0[k]  = (_Float16)wn0f[k];
  for (size_t k = i; k < 2048ull * 2048ull; k += stride) wrz1[k] = (_Float16)wrz1f[k];
  for (size_t k = i; k < 1024ull * 2048ull; k += stride) wn1[k]  = (_Float16)wn1f[k];
  for (size_t k = i; k < (size_t)ZERO_WORDS; k += stride) zbase[k] = 0u;
}

// ---------------- counters: thread-0 poll + agent RMW signal (r2-proven release) ----------------
__device__ __forceinline__ void wait_ge(u64* c, u64 tgt) {
  if (threadIdx.x == 0) {
    int g = 0;
    while (__hip_atomic_load(c, __ATOMIC_RELAXED, __HIP_MEMORY_SCOPE_AGENT) < tgt) {
      if (++g > (1 << 22)) break;      // fail loud (absmax), never hang
      __builtin_amdgcn_s_sleep(1);
    }
  }
  __syncthreads();
}
// __syncthreads drains each wave's vmcnt -> all this block's LLC stores are
// globally visible before thread 0 bumps the counter.
__device__ __forceinline__ void signal_add(u64* c) {
  __syncthreads();
  if (threadIdx.x == 0)
    __hip_atomic_fetch_add(c, 1ull, __ATOMIC_RELAXED, __HIP_MEMORY_SCOPE_AGENT);
}

// ---------------- GEMM pieces: full K per wave, M=16 rows, A shared across W-streams ----------------
// x-part (fp32 input, K=512, converted in-register), 2 W-streams
__device__ __forceinline__ void gx2(f4& a0, f4& a1, const float* __restrict__ xrow,
                                    const _Float16* __restrict__ w0,
                                    const _Float16* __restrict__ w1, int kg8) {
#pragma unroll
  for (int kw = 0; kw < 16; ++kw) {
    int k = kw * 32 + kg8;
    float4 f0 = *(const float4*)(xrow + k);
    float4 f1 = *(const float4*)(xrow + k + 4);
    h8 a;
    a[0] = (_Float16)f0.x; a[1] = (_Float16)f0.y; a[2] = (_Float16)f0.z; a[3] = (_Float16)f0.w;
    a[4] = (_Float16)f1.x; a[5] = (_Float16)f1.y; a[6] = (_Float16)f1.z; a[7] = (_Float16)f1.w;
    a0 = MFMA16(a, *(const h8*)(w0 + k), a0);
    a1 = MFMA16(a, *(const h8*)(w1 + k), a1);
  }
}
__device__ __forceinline__ void gx1(f4& a0, const float* __restrict__ xrow,
                                    const _Float16* __restrict__ w0, int kg8) {
#pragma unroll
  for (int kw = 0; kw < 16; ++kw) {
    int k = kw * 32 + kg8;
    float4 f0 = *(const float4*)(xrow + k);
    float4 f1 = *(const float4*)(xrow + k + 4);
    h8 a;
    a[0] = (_Float16)f0.x; a[1] = (_Float16)f0.y; a[2] = (_Float16)f0.z; a[3] = (_Float16)f0.w;
    a[4] = (_Float16)f1.x; a[5] = (_Float16)f1.y; a[6] = (_Float16)f1.z; a[7] = (_Float16)f1.w;
    a0 = MFMA16(a, *(const h8*)(w0 + k), a0);
  }
}
// h-part (fp16 state via LLC-bypass loads, K=1024), 1/2/3 W-streams sharing A
__device__ __forceinline__ void gh1(f4& a0, const _Float16* __restrict__ arow,
                                    const _Float16* __restrict__ w0, int kg8) {
#pragma unroll
  for (int kw = 0; kw < 32; ++kw) {
    int k = kw * 32 + kg8;
    H8U a; a.q[0] = llc_ld64(arow + k); a.q[1] = llc_ld64(arow + k + 4);
    a0 = MFMA16(a.v, *(const h8*)(w0 + k), a0);
  }
}
__device__ __forceinline__ void gh2(f4& a0, f4& a1, const _Float16* __restrict__ arow,
                                    const _Float16* __restrict__ w0,
                                    const _Float16* __restrict__ w1, int kg8) {
#pragma unroll
  for (int kw = 0; kw < 32; ++kw) {
    int k = kw * 32 + kg8;
    H8U a; a.q[0] = llc_ld64(arow + k); a.q[1] = llc_ld64(arow + k + 4);
    a0 = MFMA16(a.v, *(const h8*)(w0 + k), a0);
    a1 = MFMA16(a.v, *(const h8*)(w1 + k), a1);
  }
}
__device__ __forceinline__ void gh3(f4& a0, f4& a1, f4& a2, const _Float16* __restrict__ arow,
                                    const _Float16* __restrict__ w0,
                                    const _Float16* __restrict__ w1,
                                    const _Float16* __restrict__ w2, int kg8) {
#pragma unroll
  for (int kw = 0; kw < 32; ++kw) {
    int k = kw * 32 + kg8;
    H8U a; a.q[0] = llc_ld64(arow + k); a.q[1] = llc_ld64(arow + k + 4);
    a0 = MFMA16(a.v, *(const h8*)(w0 + k), a0);
    a1 = MFMA16(a.v, *(const h8*)(w1 + k), a1);
    a2 = MFMA16(a.v, *(const h8*)(w2 + k), a2);
  }
}

// prefetch 4 f32 gate inputs for this lane's (rows, col) — r5-proven mapping
__device__ __forceinline__ void pref4t(float* dst, const float* __restrict__ src,
                                       int colb, int mg) {
  int lane = threadIdx.x & 63;
  int col = colb + (lane & 15);
  int r0 = mg * 16 + ((lane >> 4) << 2);
#pragma unroll
  for (int j = 0; j < 4; ++j) dst[j] = llc_ldf(src + (size_t)(r0 + j) * H + col);
}

// rz apply: sigmoid; r-blocks -> rh (fp16 pair-packed), z-blocks -> zf (f32)
__device__ __forceinline__ void apply_rz(f4 a, int colb, int mg,
    const float* __restrict__ bias, bool isR, const float* hp,
    _Float16* __restrict__ rh, float* __restrict__ zf) {
  int lane = threadIdx.x & 63;
  int col = colb + (lane & 15);
  int r0 = mg * 16 + ((lane >> 4) << 2);
#pragma unroll
  for (int j = 0; j < 4; ++j) {
    float s = 1.f / (1.f + expf(-(a[j] + bias[col])));
    int row = r0 + j;
    if (isR) {
      H16B c; c.h = (_Float16)(s * hp[j]);
      unsigned pr = (unsigned)__shfl_xor((int)(unsigned)c.u, 1);
      if (!(lane & 1)) llc_st32(rh + (size_t)row * H + col, (unsigned)c.u | (pr << 16));
    } else {
      llc_st32(zf + (size_t)row * H + (col - 1024), __float_as_uint(s));
    }
  }
}

// n apply: tanh + h update -> hf (f32 master) and hh (fp16 pair-packed)
__device__ __forceinline__ void apply_n(f4 a, int colb, int mg,
    const float* __restrict__ bias, const float* pz, const float* ph,
    float* __restrict__ hfout, _Float16* __restrict__ hh) {
  int lane = threadIdx.x & 63;
  int col = colb + (lane & 15);
  int r0 = mg * 16 + ((lane >> 4) << 2);
#pragma unroll
  for (int j = 0; j < 4; ++j) {
    int row = r0 + j;
    float nn = tanhf(a[j] + bias[col]);
    float o = (1.f - pz[j]) * nn + pz[j] * ph[j];
    llc_st32(hfout + (size_t)row * H + col, __float_as_uint(o));
    H16B c; c.h = (_Float16)o;
    unsigned pr = (unsigned)__shfl_xor((int)(unsigned)c.u, 1);
    if (!(lane & 1)) llc_st32(hh + (size_t)row * H + col, (unsigned)c.u | (pr << 16));
  }
}

// ---------------- persistent GRU: 16 L0-blocks + 16 L1-blocks (t-1 lag), M=64 whole batch ----------------
__global__ __launch_bounds__(1024) void gru_main(const float* __restrict__ x,
    const _Float16* __restrict__ wrz0, const _Float16* __restrict__ wn0,
    const _Float16* __restrict__ wrz1, const _Float16* __restrict__ wn1,
    const float* __restrict__ brz0, const float* __restrict__ bn0,
    const float* __restrict__ brz1, const float* __restrict__ bn1,
    _Float16* __restrict__ h0h, _Float16* __restrict__ h1h,
    _Float16* __restrict__ rh0, _Float16* __restrict__ rh1,
    float* __restrict__ h0f, float* __restrict__ h1f,
    float* __restrict__ z0f, float* __restrict__ z1f,
    u64* __restrict__ cnt) {
  const int bid = blockIdx.x, tid = threadIdx.x;
  const int lane = tid & 63, wv = tid >> 6;
  const int mg = wv & 3, wn = wv >> 2;          // 16 waves = 4 M-groups x 4 N-groups
  const int rsub = lane & 15, kg8 = (lane >> 4) << 3;
  const int arow = mg * 16 + rsub;
  const size_t rowoff = (size_t)arow * H;
  u64* c_rz0 = cnt;      u64* c_n0 = cnt + 16;
  u64* c_rz1 = cnt + 32; u64* c_n1 = cnt + 48;
  const f4 fz = f4{0.f, 0.f, 0.f, 0.f};

  if (bid < 16) {
    // ---------- layer 0, step t: P0 rz0, P1 n0 ----------
    const int b = bid;
    const bool isR = b < 8;                     // blocks 0-7: r cols, 8-15: z cols
    const int colb0 = b * 128 + wn * 32;        // two 16-col rz tiles per wave
    const int colb1 = colb0 + 16;
    const int colbN = b * 64 + wn * 16;         // one 16-col n tile per wave
    const _Float16* wr0 = wrz0 + (size_t)(colb0 + rsub) * 1536;
    const _Float16* wr1 = wrz0 + (size_t)(colb1 + rsub) * 1536;
    const _Float16* wnp = wn0 + (size_t)(colbN + rsub) * 1536;
    const float* xr = x + (size_t)arow * 262144;
    for (int t = 0; t < 512; ++t) {
      f4 aR0 = fz, aR1 = fz, aN = fz;
      const float* xt = xr + (size_t)t * 512;
      gx2(aR0, aR1, xt, wr0, wr1, kg8);         // x-parts before any wait
      gx1(aN, xt, wnp, kg8);
      // P0: needs h0(t-1)
      wait_ge(c_n0, 16ull * (u64)t);
      float hpA[4], hpB[4];
      if (isR) { pref4t(hpA, h0f, colb0, mg); pref4t(hpB, h0f, colb1, mg); }
      gh2(aR0, aR1, h0h + (size_t)((t + 1) & 1) * 65536 + rowoff, wr0 + 512, wr1 + 512, kg8);
      apply_rz(aR0, colb0, mg, brz0, isR, hpA, rh0, z0f);
      apply_rz(aR1, colb1, mg, brz0, isR, hpB, rh0, z0f);
      signal_add(c_rz0);
      // P1: needs full rh0(t); WAR: h0h[t&1] last read by rz1(t-2)
      wait_ge(c_rz0, 16ull * (u64)(t + 1));
      if (t >= 2) wait_ge(c_rz1, 16ull * (u64)(t - 1));
      float pz4[4], ph4[4];
      pref4t(pz4, z0f, colbN, mg);
      pref4t(ph4, h0f, colbN, mg);
      gh1(aN, rh0 + rowoff, wnp + 512, kg8);
      apply_n(aN, colbN, mg, bn0, pz4, ph4, h0f, h0h + (size_t)(t & 1) * 65536);
      signal_add(c_n0);
    }
  } else {
    // ---------- layer 1, step s (lags layer 0 by ~1): P2 rz1 (+n1 h0-part), P3 n1 ----------
    const int b2 = bid - 16;
    const bool isR = b2 < 8;
    const int colb0 = b2 * 128 + wn * 32;
    const int colb1 = colb0 + 16;
    const int colbN = b2 * 64 + wn * 16;
    const _Float16* wr0 = wrz1 + (size_t)(colb0 + rsub) * 2048;
    const _Float16* wr1 = wrz1 + (size_t)(colb1 + rsub) * 2048;
    const _Float16* wnp = wn1 + (size_t)(colbN + rsub) * 2048;
    for (int s = 0; s < 512; ++s) {
      f4 aR0 = fz, aR1 = fz, aN = fz;
      // own-layer prior: h1(s-1) ready
      wait_ge(c_n1, 16ull * (u64)s);
      float hpA[4], hpB[4];
      if (isR) { pref4t(hpA, h1f, colb0, mg); pref4t(hpB, h1f, colb1, mg); }
      gh2(aR0, aR1, h1h + (size_t)((s + 1) & 1) * 65536 + rowoff, wr0 + 1024, wr1 + 1024, kg8);
      // hot: h0(s) ready; fuse n1's h0-part (3 W-streams share A)
      wait_ge(c_n0, 16ull * (u64)(s + 1));
      const _Float16* h0cur = h0h + (size_t)(s & 1) * 65536 + rowoff;
      gh3(aR0, aR1, aN, h0cur, wr0, wr1, wnp, kg8);
      apply_rz(aR0, colb0, mg, brz1, isR, hpA, rh1, z1f);
      apply_rz(aR1, colb1, mg, brz1, isR, hpB, rh1, z1f);
      signal_add(c_rz1);
      // P3: needs full rh1(s)
      wait_ge(c_rz1, 16ull * (u64)(s + 1));
      float pz4[4], ph4[4];
      pref4t(pz4, z1f, colbN, mg);
      pref4t(ph4, h1f, colbN, mg);
      gh1(aN, rh1 + rowoff, wnp + 1024, kg8);
      apply_n(aN, colbN, mg, bn1, pz4, ph4, h1f, h1h + (size_t)(s & 1) * 65536);
      signal_add(c_n1);
    }
  }
}

// ---------------- final fc: out[64,512] = h1 @ Wfc^T + bfc ----------------
__global__ __launch_bounds__(256) void fc_kernel(const float* __restrict__ h1f,
                                                 const float* __restrict__ wfc,
                                                 const float* __restrict__ bfc,
                                                 float* __restrict__ out) {
  const int bid = blockIdx.x;  // 64 blocks x 8 cols
#pragma unroll
  for (int rep = 0; rep < 2; ++rep) {
    int local = threadIdx.x + rep * 256;
    int b = local >> 3;
    int o = bid * 8 + (local & 7);
    const float4* hp = (const float4*)(h1f + (size_t)b * 1024);
    const float4* wp = (const float4*)(wfc + (size_t)o * 1024);
    float s = 0.f;
#pragma unroll 4
    for (int i2 = 0; i2 < 256; ++i2) {
      float4 hv = hp[i2], wv = wp[i2];
      s += hv.x * wv.x + hv.y * wv.y + hv.z * wv.z + hv.w * wv.w;
    }
    out[(size_t)b * 512 + o] = s + bfc[o];
  }
}

extern "C" void kernel_launch(void* const* d_in, const int* in_sizes, int n_in,
                              void* d_out, int out_size, void* d_ws, size_t ws_size,
                              hipStream_t stream) {
  const float* x    = (const float*)d_in[0];
  const float* Wrz0 = (const float*)d_in[1];
  const float* brz0 = (const float*)d_in[2];
  const float* Wn0  = (const float*)d_in[3];
  const float* bn0  = (const float*)d_in[4];
  const float* Wrz1 = (const float*)d_in[5];
  const float* brz1 = (const float*)d_in[6];
  const float* Wn1  = (const float*)d_in[7];
  const float* bn1  = (const float*)d_in[8];
  const float* Wfc  = (const float*)d_in[9];
  const float* bfc  = (const float*)d_in[10];
  float* out = (float*)d_out;
  char* ws = (char*)d_ws;

  _Float16* wrz0h = (_Float16*)(ws + OFF_WRZ0);
  _Float16* wn0h  = (_Float16*)(ws + OFF_WN0);
  _Float16* wrz1h = (_Float16*)(ws + OFF_WRZ1);
  _Float16* wn1h  = (_Float16*)(ws + OFF_WN1);
  _Float16* h0h   = (_Float16*)(ws + OFF_H0H);
  _Float16* h1h   = (_Float16*)(ws + OFF_H1H);
  _Float16* rh0   = (_Float16*)(ws + OFF_RH0);
  _Float16* rh1   = (_Float16*)(ws + OFF_RH1);
  float* h0f = (float*)(ws + OFF_H0F);
  float* h1f = (float*)(ws + OFF_H1F);
  float* z0f = (float*)(ws + OFF_Z0F);
  float* z1f = (float*)(ws + OFF_Z1F);
  u64* cnt = (u64*)(ws + OFF_CNT);

  prep_kernel<<<2048, 256, 0, stream>>>(Wrz0, Wn0, Wrz1, Wn1,
                                        wrz0h, wn0h, wrz1h, wn1h,
                                        (unsigned*)(ws + OFF_H0H));
  gru_main<<<32, 1024, 0, stream>>>(x, wrz0h, wn0h, wrz1h, wn1h,
                                    brz0, bn0, brz1, bn1,
                                    h0h, h1h, rh0, rh1,
                                    h0f, h1f, z0f, z1f, cnt);
  fc_kernel<<<64, 256, 0, stream>>>(h1f, Wfc, bfc, out);
}

// Round 7
// 40630.255 us; speedup vs baseline: 2.2264x; 2.2264x over previous
//
#include <hip/hip_runtime.h>
#include <math.h>

typedef _Float16 h8 __attribute__((ext_vector_type(8)));
typedef float f4 __attribute__((ext_vector_type(4)));
typedef unsigned long long u64;

#define H 1024

// ---- workspace layout (bytes) ----
#define OFF_WRZ0 0ull            // fp16 [2048][1536]
#define OFF_WN0  6291456ull      // fp16 [1024][1536]
#define OFF_WRZ1 9437184ull      // fp16 [2048][2048]
#define OFF_WN1  17825792ull     // fp16 [1024][2048]
#define OFF_H0H  22020096ull     // fp16 [2][64][1024] parity
#define OFF_H1H  22282240ull     // fp16 [2][64][1024]
#define OFF_RH0  22544384ull     // fp16 [64][1024]
#define OFF_RH1  22675456ull     // fp16 [64][1024]
#define OFF_H0F  22806528ull     // f32 [64][1024]
#define OFF_H1F  23068672ull     // f32 [64][1024]
#define OFF_Z0F  23330816ull     // f32 [64][1024]
#define OFF_Z1F  23592960ull     // f32 [64][1024]
#define OFF_CNT  23855104ull     // u64 [5 ctr] stride 16 u64 (128B)
#define OFF_XR   23856128ull     // f32 ring [8][64][3072] = 6291456 B
#define ZERO_WORDS 458912        // (23855744 - 22020096)/4

// ---------------- LLC-bypass (agent-scope relaxed) — r2/r3/r5-proven ----------------
__device__ __forceinline__ u64 llc_ld64(const void* p) {
  return __hip_atomic_load((const u64*)p, __ATOMIC_RELAXED, __HIP_MEMORY_SCOPE_AGENT);
}
__device__ __forceinline__ unsigned llc_ld32(const void* p) {
  return __hip_atomic_load((const unsigned*)p, __ATOMIC_RELAXED, __HIP_MEMORY_SCOPE_AGENT);
}
__device__ __forceinline__ float llc_ldf(const float* p) {
  return __uint_as_float(llc_ld32(p));
}
__device__ __forceinline__ void llc_st32(void* p, unsigned v) {
  __hip_atomic_store((unsigned*)p, v, __ATOMIC_RELAXED, __HIP_MEMORY_SCOPE_AGENT);
}
union H16B { _Float16 h; unsigned short u; };

#define MFMA16(a, b, c) __builtin_amdgcn_mfma_f32_16x16x32_f16((a), (b), (c), 0, 0, 0)

// ---------------- prep ----------------
__global__ __launch_bounds__(256) void prep_kernel(
    const float* __restrict__ wrz0f, const float* __restrict__ wn0f,
    const float* __restrict__ wrz1f, const float* __restrict__ wn1f,
    _Float16* __restrict__ wrz0, _Float16* __restrict__ wn0,
    _Float16* __restrict__ wrz1, _Float16* __restrict__ wn1,
    unsigned* __restrict__ zbase) {
  size_t i = (size_t)blockIdx.x * blockDim.x + threadIdx.x;
  size_t stride = (size_t)gridDim.x * blockDim.x;
  for (size_t k = i; k < 2048ull * 1536ull; k += stride) wrz0[k] = (_Float16)wrz0f[k];
  for (size_t k = i; k < 1024ull * 1536ull; k += stride) wn0[k]  = (_Float16)wn0f[k];
  for (size_t k = i; k < 2048ull * 2048ull; k += stride) wrz1[k] = (_Float16)wrz1f[k];
  for (size_t k = i; k < 1024ull * 2048ull; k += stride) wn1[k]  = (_Float16)wn1f[k];
  for (size_t k = i; k < (size_t)ZERO_WORDS; k += stride) zbase[k] = 0u;
}

// ---------------- counters (thread0 poll, vmcnt-drain release) ----------------
__device__ __forceinline__ void wait_ge(u64* c, u64 tgt, int* sdead) {
  if (threadIdx.x == 0 && *sdead == 0) {
    int g = 0;
    while (__hip_atomic_load(c, __ATOMIC_RELAXED, __HIP_MEMORY_SCOPE_AGENT) < tgt) {
      if (++g > (1 << 20)) { *sdead = 1; break; }   // fail loud, never hang
      __builtin_amdgcn_s_sleep(1);
    }
  }
  __syncthreads();
}
__device__ __forceinline__ void signal_add(u64* c) {
  __syncthreads();   // drains all waves' vmcnt: LLC stores visible before bump
  if (threadIdx.x == 0)
    __hip_atomic_fetch_add(c, 1ull, __ATOMIC_RELAXED, __HIP_MEMORY_SCOPE_AGENT);
}

// ---------------- stage full 128KB state -> LDS (swizzled), issue-all-then-write ----------------
__device__ __forceinline__ void stage128(const _Float16* __restrict__ src,
                                         char* __restrict__ sA) {
  const int tid = threadIdx.x;
  u64 tmp[16];
#pragma unroll
  for (int i = 0; i < 16; ++i) {
    int u = tid + (i << 10);                  // 16384 u64 units (4 fp16 each)
    tmp[i] = llc_ld64(src + ((size_t)u << 2));
  }
#pragma unroll
  for (int i = 0; i < 16; ++i) {
    int u = tid + (i << 10);
    int row = u >> 8, q = u & 255;            // 256 u64 per 2KB row
    unsigned byt = (((unsigned)row << 11) + ((unsigned)q << 3)) ^ (((unsigned)(row & 7)) << 4);
    *(u64*)(sA + byt) = tmp[i];
  }
}

// ---------------- GEMM: one 16x16 tile, full K=1024, A from swizzled LDS ----------------
__device__ __forceinline__ void gemmL1(const char* __restrict__ sA, int arow,
                                       const _Float16* __restrict__ w, int kg8, f4& acc) {
  const unsigned rb = ((unsigned)arow << 11);
  const unsigned swz = ((unsigned)(arow & 7)) << 4;
#pragma unroll
  for (int kw = 0; kw < 32; ++kw) {
    int k = kw * 32 + kg8;
    h8 a = *(const h8*)(sA + ((rb + ((unsigned)k << 1)) ^ swz));
    acc = MFMA16(a, *(const h8*)(w + k), acc);
  }
}

// prefetch 4 gate values at (rows, col) — r5/r6-proven fragment mapping
__device__ __forceinline__ void pref4t(float* dst, const float* __restrict__ src,
                                       int colb, int mg, int ldm) {
  int lane = threadIdx.x & 63;
  int col = colb + (lane & 15);
  int r0 = mg * 16 + ((lane >> 4) << 2);
#pragma unroll
  for (int j = 0; j < 4; ++j) dst[j] = llc_ldf(src + (size_t)(r0 + j) * ldm + col);
}

// rz apply: sigmoid; r-blocks -> rh (fp16 pair-packed), z-blocks -> zf
__device__ __forceinline__ void apply_rz2(f4 a, int colb, int mg,
    const float* __restrict__ bias, bool isR, const float* hp, const float* xp,
    _Float16* __restrict__ rh, float* __restrict__ zf) {
  int lane = threadIdx.x & 63;
  int col = colb + (lane & 15);
  int r0 = mg * 16 + ((lane >> 4) << 2);
#pragma unroll
  for (int j = 0; j < 4; ++j) {
    float v = a[j] + bias[col] + (xp ? xp[j] : 0.f);
    float s = 1.f / (1.f + expf(-v));
    int row = r0 + j;
    if (isR) {
      H16B c; c.h = (_Float16)(s * hp[j]);
      unsigned pr = (unsigned)__shfl_xor((int)(unsigned)c.u, 1);
      if (!(lane & 1)) llc_st32(rh + (size_t)row * H + col, (unsigned)c.u | (pr << 16));
    } else {
      llc_st32(zf + (size_t)row * H + (col - 1024), __float_as_uint(s));
    }
  }
}

// n apply: tanh + h update -> hf (f32 master) + hh (fp16 pair-packed)
__device__ __forceinline__ void apply_n2(f4 a, int colb, int mg,
    const float* __restrict__ bias, const float* pz, const float* ph, const float* xp,
    float* __restrict__ hfout, _Float16* __restrict__ hh) {
  int lane = threadIdx.x & 63;
  int col = colb + (lane & 15);
  int r0 = mg * 16 + ((lane >> 4) << 2);
#pragma unroll
  for (int j = 0; j < 4; ++j) {
    int row = r0 + j;
    float v = a[j] + bias[col] + (xp ? xp[j] : 0.f);
    float nn = tanhf(v);
    float o = (1.f - pz[j]) * nn + pz[j] * ph[j];
    llc_st32(hfout + (size_t)row * H + col, __float_as_uint(o));
    H16B c; c.h = (_Float16)o;
    unsigned pr = (unsigned)__shfl_xor((int)(unsigned)c.u, 1);
    if (!(lane & 1)) llc_st32(hh + (size_t)row * H + col, (unsigned)c.u | (pr << 16));
  }
}

// ---------------- persistent GRU ----------------
// blocks 0..31: L0 (step t); 32..63: L1 (step s, lag 1); 64..79: xproj (run-ahead ring)
__global__ __launch_bounds__(1024) void gru_main(const float* __restrict__ x,
    const _Float16* __restrict__ wrz0, const _Float16* __restrict__ wn0,
    const _Float16* __restrict__ wrz1, const _Float16* __restrict__ wn1,
    const float* __restrict__ brz0, const float* __restrict__ bn0,
    const float* __restrict__ brz1, const float* __restrict__ bn1,
    _Float16* __restrict__ h0h, _Float16* __restrict__ h1h,
    _Float16* __restrict__ rh0, _Float16* __restrict__ rh1,
    float* __restrict__ h0f, float* __restrict__ h1f,
    float* __restrict__ z0f, float* __restrict__ z1f,
    float* __restrict__ xring, u64* __restrict__ cnt) {
  __shared__ char sA[131072];
  __shared__ int sdead;
  const int bid = blockIdx.x, tid = threadIdx.x;
  const int lane = tid & 63, wv = tid >> 6;
  const int mg = wv & 3, wsel = wv >> 2;
  const int rsub = lane & 15, kg8 = (lane >> 4) << 3;
  const int arow = mg * 16 + rsub;
  if (tid == 0) sdead = 0;
  __syncthreads();
  u64* c_rz0 = cnt;      u64* c_n0 = cnt + 16;
  u64* c_rz1 = cnt + 32; u64* c_n1 = cnt + 48;
  u64* c_xp  = cnt + 64;
  const f4 fz = f4{0.f, 0.f, 0.f, 0.f};

  if (bid < 32) {
    // ---------- layer 0 ----------
    const int b = bid;
    const bool isR = b < 16;
    const int colbRZ = b * 64 + wsel * 16;          // all 16 waves: one rz tile
    const int colbN  = b * 32 + (wsel & 1) * 16;    // waves wsel<2: one n tile
    const _Float16* wRZ = wrz0 + (size_t)(colbRZ + rsub) * 1536 + 512;  // h-part
    const _Float16* wN  = wn0 + (size_t)(colbN + rsub) * 1536 + 512;   // rh-part
    for (int t = 0; t < 512; ++t) {
      // xproj values for this step (run-ahead ring; wait usually satisfied)
      wait_ge(c_xp, 16ull * (u64)(t + 1), &sdead);
      const float* xrs = xring + (size_t)(t & 7) * 196608;
      float xpR[4], xpN[4];
      pref4t(xpR, xrs, colbRZ, mg, 3072);
      if (wsel < 2) pref4t(xpN, xrs, 2048 + colbN, mg, 3072);
      // ---- P0: rz0(t) ----
      wait_ge(c_n0, 32ull * (u64)t, &sdead);
      stage128(h0h + (size_t)((t + 1) & 1) * 65536, sA);
      float hp[4];
      if (isR) pref4t(hp, h0f, colbRZ, mg, H);
      __syncthreads();
      f4 aR = fz;
      gemmL1(sA, arow, wRZ, kg8, aR);
      apply_rz2(aR, colbRZ, mg, brz0, isR, hp, xpR, rh0, z0f);
      signal_add(c_rz0);
      // ---- P1: n0(t) ----
      wait_ge(c_rz0, 32ull * (u64)(t + 1), &sdead);
      if (t >= 2) wait_ge(c_rz1, 32ull * (u64)(t - 1), &sdead);  // h0h[t&1] WAR
      stage128(rh0, sA);
      float pz4[4], ph4[4];
      if (wsel < 2) { pref4t(pz4, z0f, colbN, mg, H); pref4t(ph4, h0f, colbN, mg, H); }
      __syncthreads();
      if (wsel < 2) {
        f4 aN = fz;
        gemmL1(sA, arow, wN, kg8, aN);
        apply_n2(aN, colbN, mg, bn0, pz4, ph4, xpN, h0f, h0h + (size_t)(t & 1) * 65536);
      }
      signal_add(c_n0);
    }
  } else if (bid < 64) {
    // ---------- layer 1, step s ----------
    const int b2 = bid - 32;
    const bool isR = b2 < 16;
    const int colbRZ = b2 * 64 + wsel * 16;
    const int colbN  = b2 * 32 + (wsel & 1) * 16;
    const _Float16* wRZh1 = wrz1 + (size_t)(colbRZ + rsub) * 2048 + 1024;
    const _Float16* wRZh0 = wrz1 + (size_t)(colbRZ + rsub) * 2048;
    const _Float16* wNh0  = wn1 + (size_t)(colbN + rsub) * 2048;
    const _Float16* wNrh  = wn1 + (size_t)(colbN + rsub) * 2048 + 1024;
    for (int s = 0; s < 512; ++s) {
      // ---- P2: rz1(s) ---- pre-hot: h1-part
      wait_ge(c_n1, 32ull * (u64)s, &sdead);
      stage128(h1h + (size_t)((s + 1) & 1) * 65536, sA);
      float hp[4];
      if (isR) pref4t(hp, h1f, colbRZ, mg, H);
      __syncthreads();
      f4 aR = fz, aN = fz;
      gemmL1(sA, arow, wRZh1, kg8, aR);
      // hot: h0(s) ready
      wait_ge(c_n0, 32ull * (u64)(s + 1), &sdead);
      stage128(h0h + (size_t)(s & 1) * 65536, sA);
      __syncthreads();
      gemmL1(sA, arow, wRZh0, kg8, aR);
      if (wsel < 2) gemmL1(sA, arow, wNh0, kg8, aN);
      apply_rz2(aR, colbRZ, mg, brz1, isR, hp, nullptr, rh1, z1f);
      signal_add(c_rz1);
      // ---- P3: n1(s) ----
      wait_ge(c_rz1, 32ull * (u64)(s + 1), &sdead);
      stage128(rh1, sA);
      float pz4[4], ph4[4];
      if (wsel < 2) { pref4t(pz4, z1f, colbN, mg, H); pref4t(ph4, h1f, colbN, mg, H); }
      __syncthreads();
      if (wsel < 2) {
        gemmL1(sA, arow, wNrh, kg8, aN);
        apply_n2(aN, colbN, mg, bn1, pz4, ph4, nullptr, h1f, h1h + (size_t)(s & 1) * 65536);
      }
      signal_add(c_n1);
    }
  } else {
    // ---------- xproj: block xb covers all 64 rows x cols [xb*192, +192) ----------
    const int xb = bid - 64;                      // 0..15
    const int rg = wsel;                          // wave row-group
    const int wq = mg;                            // wave col-subgroup (3 tiles)
    const float* xrow = x + (size_t)(rg * 16 + rsub) * 262144;
    const _Float16* wp[3];
    int colb[3];
#pragma unroll
    for (int c = 0; c < 3; ++c) {
      colb[c] = xb * 192 + (wq * 3 + c) * 16;
      wp[c] = (colb[c] < 2048) ? wrz0 + (size_t)(colb[c] + rsub) * 1536
                               : wn0 + (size_t)(colb[c] - 2048 + rsub) * 1536;
    }
    for (int t = 0; t < 512; ++t) {
      if (t >= 8) wait_ge(c_n0, 32ull * (u64)(t - 7), &sdead);   // ring WAR
      f4 acc[3] = { fz, fz, fz };
      const float* xt = xrow + (size_t)t * 512;
#pragma unroll
      for (int kw = 0; kw < 16; ++kw) {
        int k = kw * 32 + kg8;
        float4 f0 = *(const float4*)(xt + k);
        float4 f1 = *(const float4*)(xt + k + 4);
        h8 a;
        a[0] = (_Float16)f0.x; a[1] = (_Float16)f0.y; a[2] = (_Float16)f0.z; a[3] = (_Float16)f0.w;
        a[4] = (_Float16)f1.x; a[5] = (_Float16)f1.y; a[6] = (_Float16)f1.z; a[7] = (_Float16)f1.w;
#pragma unroll
        for (int c = 0; c < 3; ++c)
          acc[c] = MFMA16(a, *(const h8*)(wp[c] + k), acc[c]);
      }
      float* xrs = xring + (size_t)(t & 7) * 196608;
      const int r0 = rg * 16 + ((lane >> 4) << 2);
      const int csub = lane & 15;
#pragma unroll
      for (int c = 0; c < 3; ++c)
#pragma unroll
        for (int j = 0; j < 4; ++j)
          llc_st32(xrs + (size_t)(r0 + j) * 3072 + colb[c] + csub,
                   __float_as_uint(acc[c][j]));
      signal_add(c_xp);
    }
  }
}

// ---------------- final fc ----------------
__global__ __launch_bounds__(256) void fc_kernel(const float* __restrict__ h1f,
                                                 const float* __restrict__ wfc,
                                                 const float* __restrict__ bfc,
                                                 float* __restrict__ out) {
  const int bid = blockIdx.x;
#pragma unroll
  for (int rep = 0; rep < 2; ++rep) {
    int local = threadIdx.x + rep * 256;
    int b = local >> 3;
    int o = bid * 8 + (local & 7);
    const float4* hp = (const float4*)(h1f + (size_t)b * 1024);
    const float4* wp = (const float4*)(wfc + (size_t)o * 1024);
    float s = 0.f;
#pragma unroll 4
    for (int i2 = 0; i2 < 256; ++i2) {
      float4 hv = hp[i2], wv = wp[i2];
      s += hv.x * wv.x + hv.y * wv.y + hv.z * wv.z + hv.w * wv.w;
    }
    out[(size_t)b * 512 + o] = s + bfc[o];
  }
}

extern "C" void kernel_launch(void* const* d_in, const int* in_sizes, int n_in,
                              void* d_out, int out_size, void* d_ws, size_t ws_size,
                              hipStream_t stream) {
  const float* x    = (const float*)d_in[0];
  const float* Wrz0 = (const float*)d_in[1];
  const float* brz0 = (const float*)d_in[2];
  const float* Wn0  = (const float*)d_in[3];
  const float* bn0  = (const float*)d_in[4];
  const float* Wrz1 = (const float*)d_in[5];
  const float* brz1 = (const float*)d_in[6];
  const float* Wn1  = (const float*)d_in[7];
  const float* bn1  = (const float*)d_in[8];
  const float* Wfc  = (const float*)d_in[9];
  const float* bfc  = (const float*)d_in[10];
  float* out = (float*)d_out;
  char* ws = (char*)d_ws;

  _Float16* wrz0h = (_Float16*)(ws + OFF_WRZ0);
  _Float16* wn0h  = (_Float16*)(ws + OFF_WN0);
  _Float16* wrz1h = (_Float16*)(ws + OFF_WRZ1);
  _Float16* wn1h  = (_Float16*)(ws + OFF_WN1);
  _Float16* h0h   = (_Float16*)(ws + OFF_H0H);
  _Float16* h1h   = (_Float16*)(ws + OFF_H1H);
  _Float16* rh0   = (_Float16*)(ws + OFF_RH0);
  _Float16* rh1   = (_Float16*)(ws + OFF_RH1);
  float* h0f = (float*)(ws + OFF_H0F);
  float* h1f = (float*)(ws + OFF_H1F);
  float* z0f = (float*)(ws + OFF_Z0F);
  float* z1f = (float*)(ws + OFF_Z1F);
  float* xring = (float*)(ws + OFF_XR);
  u64* cnt = (u64*)(ws + OFF_CNT);

  prep_kernel<<<2048, 256, 0, stream>>>(Wrz0, Wn0, Wrz1, Wn1,
                                        wrz0h, wn0h, wrz1h, wn1h,
                                        (unsigned*)(ws + OFF_H0H));
  gru_main<<<80, 1024, 0, stream>>>(x, wrz0h, wn0h, wrz1h, wn1h,
                                    brz0, bn0, brz1, bn1,
                                    h0h, h1h, rh0, rh1,
                                    h0f, h1f, z0f, z1f, xring, cnt);
  fc_kernel<<<64, 256, 0, stream>>>(h1f, Wfc, bfc, out);
}